// Round 1
// baseline (681.413 us; speedup 1.0000x reference)
//
#include <hip/hip_runtime.h>
#include <math.h>

#define B_ 2
#define H_ 8
#define C_ 2048
#define E_ 1024
#define D_ 64
#define KP_ 8
#define P_ 16
#define HD_ 512              // H*D
#define ROWS_ 32768          // B*H*C
#define M_ 4096              // B*C

// ---------------------------------------------------------------------------
// GEMM 1: QKV projections.  x (4096 x 1024) @ W (1024 x 512) -> (b,h,c,d)
// layout with 1/sqrt(d) scaling on Q and K.  z selects which projection.
// 128x128 block tile, 256 threads, 8x8 per-thread microtile, BK=8.
// ---------------------------------------------------------------------------
__global__ __launch_bounds__(256) void gemm_qkv_kernel(
    const float* __restrict__ x,
    const float* __restrict__ Wq, const float* __restrict__ Wk,
    const float* __restrict__ Wv,
    float* __restrict__ Qt, float* __restrict__ Kt, float* __restrict__ Vt)
{
    const int z = blockIdx.z;
    const float* __restrict__ W = (z == 0) ? Wq : (z == 1) ? Wk : Wv;
    float* __restrict__ Out = (z == 0) ? Qt : (z == 1) ? Kt : Vt;
    const float scale = (z == 2) ? 1.0f : 0.125f;   // 1/sqrt(64)

    const int K = E_;      // 1024
    const int N = HD_;     // 512
    const int m0 = blockIdx.y * 128;
    const int n0 = blockIdx.x * 128;
    const int tid = threadIdx.x;
    const int tx = tid & 15;       // n direction
    const int ty = tid >> 4;       // m direction

    __shared__ float As[8][128];   // transposed A tile: As[k][m]
    __shared__ float Bs[8][128];   // Bs[k][n]

    float acc[8][8];
#pragma unroll
    for (int i = 0; i < 8; ++i)
#pragma unroll
        for (int j = 0; j < 8; ++j) acc[i][j] = 0.0f;

    const int ar = tid >> 1;          // 0..127 row in tile
    const int ak = (tid & 1) * 4;     // 0 or 4
    const int bk = tid >> 5;          // 0..7
    const int bn = (tid & 31) * 4;    // 0..124

    for (int k0 = 0; k0 < K; k0 += 8) {
        const float4 av = *(const float4*)(x + (size_t)(m0 + ar) * K + k0 + ak);
        const float4 bv = *(const float4*)(W + (size_t)(k0 + bk) * N + n0 + bn);
        __syncthreads();
        As[ak + 0][ar] = av.x;
        As[ak + 1][ar] = av.y;
        As[ak + 2][ar] = av.z;
        As[ak + 3][ar] = av.w;
        *(float4*)&Bs[bk][bn] = bv;
        __syncthreads();
#pragma unroll
        for (int k = 0; k < 8; ++k) {
            const float4 a0 = *(const float4*)&As[k][ty * 4];
            const float4 a1 = *(const float4*)&As[k][ty * 4 + 64];
            const float4 b0 = *(const float4*)&Bs[k][tx * 4];
            const float4 b1 = *(const float4*)&Bs[k][tx * 4 + 64];
            const float a[8] = {a0.x, a0.y, a0.z, a0.w, a1.x, a1.y, a1.z, a1.w};
            const float bb[8] = {b0.x, b0.y, b0.z, b0.w, b1.x, b1.y, b1.z, b1.w};
#pragma unroll
            for (int i = 0; i < 8; ++i)
#pragma unroll
                for (int j = 0; j < 8; ++j)
                    acc[i][j] = fmaf(a[i], bb[j], acc[i][j]);
        }
    }

    // store to (b,h,c,d) layout
#pragma unroll
    for (int ih = 0; ih < 2; ++ih) {
#pragma unroll
        for (int ii = 0; ii < 4; ++ii) {
            const int m = m0 + ih * 64 + ty * 4 + ii;
            const int b = m >> 11;
            const int c = m & (C_ - 1);
#pragma unroll
            for (int jh = 0; jh < 2; ++jh) {
                const int n = n0 + jh * 64 + tx * 4;
                const int h = n >> 6;
                const int d = n & 63;
                float4 v;
                v.x = acc[ih * 4 + ii][jh * 4 + 0] * scale;
                v.y = acc[ih * 4 + ii][jh * 4 + 1] * scale;
                v.z = acc[ih * 4 + ii][jh * 4 + 2] * scale;
                v.w = acc[ih * 4 + ii][jh * 4 + 3] * scale;
                *(float4*)&Out[(((size_t)(b * H_ + h) * C_ + c) << 6) + d] = v;
            }
        }
    }
}

// ---------------------------------------------------------------------------
// GEMM 2: united (4096 x 512) @ Wu (512 x 1024) + bu -> new_out (row-major)
// ---------------------------------------------------------------------------
__global__ __launch_bounds__(256) void gemm_out_kernel(
    const float* __restrict__ U, const float* __restrict__ Wu,
    const float* __restrict__ bu, float* __restrict__ out)
{
    const int K = HD_;     // 512
    const int N = E_;      // 1024
    const int m0 = blockIdx.y * 128;
    const int n0 = blockIdx.x * 128;
    const int tid = threadIdx.x;
    const int tx = tid & 15;
    const int ty = tid >> 4;

    __shared__ float As[8][128];
    __shared__ float Bs[8][128];

    float acc[8][8];
#pragma unroll
    for (int i = 0; i < 8; ++i)
#pragma unroll
        for (int j = 0; j < 8; ++j) acc[i][j] = 0.0f;

    const int ar = tid >> 1;
    const int ak = (tid & 1) * 4;
    const int bk = tid >> 5;
    const int bn = (tid & 31) * 4;

    for (int k0 = 0; k0 < K; k0 += 8) {
        const float4 av = *(const float4*)(U + (size_t)(m0 + ar) * K + k0 + ak);
        const float4 bv = *(const float4*)(Wu + (size_t)(k0 + bk) * N + n0 + bn);
        __syncthreads();
        As[ak + 0][ar] = av.x;
        As[ak + 1][ar] = av.y;
        As[ak + 2][ar] = av.z;
        As[ak + 3][ar] = av.w;
        *(float4*)&Bs[bk][bn] = bv;
        __syncthreads();
#pragma unroll
        for (int k = 0; k < 8; ++k) {
            const float4 a0 = *(const float4*)&As[k][ty * 4];
            const float4 a1 = *(const float4*)&As[k][ty * 4 + 64];
            const float4 b0 = *(const float4*)&Bs[k][tx * 4];
            const float4 b1 = *(const float4*)&Bs[k][tx * 4 + 64];
            const float a[8] = {a0.x, a0.y, a0.z, a0.w, a1.x, a1.y, a1.z, a1.w};
            const float bb[8] = {b0.x, b0.y, b0.z, b0.w, b1.x, b1.y, b1.z, b1.w};
#pragma unroll
            for (int i = 0; i < 8; ++i)
#pragma unroll
                for (int j = 0; j < 8; ++j)
                    acc[i][j] = fmaf(a[i], bb[j], acc[i][j]);
        }
    }

#pragma unroll
    for (int ih = 0; ih < 2; ++ih) {
#pragma unroll
        for (int ii = 0; ii < 4; ++ii) {
            const int m = m0 + ih * 64 + ty * 4 + ii;
#pragma unroll
            for (int jh = 0; jh < 2; ++jh) {
                const int n = n0 + jh * 64 + tx * 4;
                const float4 bias = *(const float4*)&bu[n];
                float4 v;
                v.x = acc[ih * 4 + ii][jh * 4 + 0] + bias.x;
                v.y = acc[ih * 4 + ii][jh * 4 + 1] + bias.y;
                v.z = acc[ih * 4 + ii][jh * 4 + 2] + bias.z;
                v.w = acc[ih * 4 + ii][jh * 4 + 3] + bias.w;
                *(float4*)&out[(size_t)m * N + n] = v;
            }
        }
    }
}

// ---------------------------------------------------------------------------
// Kernel 2: density sums over the context axis.
// One thread per (b,h,c) row; wave-butterfly reduce each of the 128 (p,kk)
// slots across 64 rows, then lane 0 global-atomicAdds into S[bh][p][kk].
// ---------------------------------------------------------------------------
__global__ __launch_bounds__(256) void dens_sum_kernel(
    const float* __restrict__ means, const float* __restrict__ sigmas,
    float* __restrict__ S)
{
    const int row = blockIdx.x * 256 + threadIdx.x;   // 0..32767
    const int lane = threadIdx.x & 63;
    const int bh = row >> 11;                          // same for whole wave

    const float* mrow = means + (size_t)row * 8;
    const float* srow = sigmas + (size_t)row * 8;
    const float4 ma = *(const float4*)(mrow);
    const float4 mb = *(const float4*)(mrow + 4);
    const float4 sa = *(const float4*)(srow);
    const float4 sb = *(const float4*)(srow + 4);
    const float mm[8] = {ma.x, ma.y, ma.z, ma.w, mb.x, mb.y, mb.z, mb.w};
    const float sg[8] = {sa.x, sa.y, sa.z, sa.w, sb.x, sb.y, sb.z, sb.w};

    int idx[16];
#pragma unroll
    for (int j = 0; j < 8; ++j) {
        int i0 = (int)floorf(mm[j]);
        i0 = min(max(i0, 0), C_ - 1);
        const int i1 = min(i0 + 1, C_ - 1);
        idx[2 * j] = i0;
        idx[2 * j + 1] = i1;
    }
    unsigned dupm = 0;
#pragma unroll
    for (int p = 1; p < 16; ++p) {
        bool d = false;
#pragma unroll
        for (int q = 0; q < 15; ++q)
            if (q < p) d = d || (idx[q] == idx[p]);
        if (d) dupm |= (1u << p);
    }

#pragma unroll
    for (int p = 0; p < 16; ++p) {
        const float fi = (float)idx[p];
        const bool dup = (dupm >> p) & 1u;
#pragma unroll
        for (int kk = 0; kk < 8; ++kk) {
            const float t = (fi - mm[kk]) / sg[kk];
            float val = dup ? 0.0f : expf(-0.5f * t * t);
#pragma unroll
            for (int off = 1; off < 64; off <<= 1)
                val += __shfl_xor(val, off);
            if (lane == 0)
                atomicAdd(&S[bh * 128 + p * 8 + kk], val);
        }
    }
}

// ---------------------------------------------------------------------------
// Kernel 3: attention core.  One wave per (b,h,c) row; lane = head dim d.
//  - lanes 0..15 compute per-point weights w[p] (dup-aware, S-normalized)
//  - dots via per-p wave butterfly reduction
//  - redundant per-lane 16-way softmax
//  - V-combine into united (b,c,h*d)
//  - full 2048-float attentions row written via LDS scatter buffer
// ---------------------------------------------------------------------------
__global__ __launch_bounds__(256) void attn_kernel(
    const float* __restrict__ means, const float* __restrict__ sigmas,
    const float* __restrict__ values, const float* __restrict__ S,
    const float* __restrict__ Qt, const float* __restrict__ Kt,
    const float* __restrict__ Vt, float* __restrict__ united,
    float* __restrict__ attn)
{
    __shared__ float rowbuf[4][2048];   // 32 KiB
    const int w = threadIdx.x >> 6;
    const int lane = threadIdx.x & 63;
    const int row = blockIdx.x * 4 + w;          // 0..32767
    const int bh = row >> 11;
    const int c = row & (C_ - 1);
    const int b = bh >> 3;
    const int h = bh & 7;

    const float* mrow = means + (size_t)row * 8;
    const float4 ma = *(const float4*)(mrow);
    const float4 mb = *(const float4*)(mrow + 4);
    const float mm[8] = {ma.x, ma.y, ma.z, ma.w, mb.x, mb.y, mb.z, mb.w};

    int idx[16];
#pragma unroll
    for (int j = 0; j < 8; ++j) {
        int i0 = (int)floorf(mm[j]);
        i0 = min(max(i0, 0), C_ - 1);
        const int i1 = min(i0 + 1, C_ - 1);
        idx[2 * j] = i0;
        idx[2 * j + 1] = i1;
    }
    int myidx = 0;
#pragma unroll
    for (int p = 0; p < 16; ++p)
        if (p == lane) myidx = idx[p];

    // ---- per-point weights on lanes 0..15 ----
    float wp = 0.0f;
    if (lane < 16) {
        bool dup = false;
#pragma unroll
        for (int q = 0; q < 15; ++q)
            dup = dup || ((q < lane) && (idx[q] == myidx));
        if (!dup) {
            const float* srow = sigmas + (size_t)row * 8;
            const float* vrow = values + (size_t)row * 8;
            const float4 sa = *(const float4*)(srow);
            const float4 sb = *(const float4*)(srow + 4);
            const float4 va = *(const float4*)(vrow);
            const float4 vb = *(const float4*)(vrow + 4);
            const float sg[8] = {sa.x, sa.y, sa.z, sa.w, sb.x, sb.y, sb.z, sb.w};
            const float vl[8] = {va.x, va.y, va.z, va.w, vb.x, vb.y, vb.z, vb.w};
            const float* Sp = S + bh * 128 + lane * 8;
            const float4 Sa = *(const float4*)(Sp);
            const float4 Sb = *(const float4*)(Sp + 4);
            const float Sv[8] = {Sa.x, Sa.y, Sa.z, Sa.w, Sb.x, Sb.y, Sb.z, Sb.w};
            const float fi = (float)myidx;
#pragma unroll
            for (int kk = 0; kk < 8; ++kk) {
                const float t = (fi - mm[kk]) / sg[kk];
                const float e = expf(-0.5f * t * t);
                wp = fmaf(vl[kk], e / (Sv[kk] + 1e-8f), wp);
            }
        }
    }
    float wv[16];
#pragma unroll
    for (int p = 0; p < 16; ++p) wv[p] = __shfl(wp, p);

    // ---- dots: Q . K[idx[p]] over d=64 ----
    const float qv = Qt[((size_t)row << 6) + lane];
    const float* Kbh = Kt + ((size_t)bh << 17);
    float logit[16];
#pragma unroll
    for (int p = 0; p < 16; ++p) {
        float prod = qv * Kbh[((size_t)idx[p] << 6) + lane];
#pragma unroll
        for (int off = 1; off < 64; off <<= 1)
            prod += __shfl_xor(prod, off);
        logit[p] = wv[p] * prod;
    }

    // ---- softmax over 16 points (redundant on all lanes) ----
    float mx = logit[0];
#pragma unroll
    for (int p = 1; p < 16; ++p) mx = fmaxf(mx, logit[p]);
    float se = 0.0f;
#pragma unroll
    for (int p = 0; p < 16; ++p) {
        logit[p] = expf(logit[p] - mx);
        se += logit[p];
    }
    const float inv = 1.0f / se;
    float mysm = 0.0f;
#pragma unroll
    for (int p = 0; p < 16; ++p) {
        logit[p] *= inv;
        if (p == lane) mysm = logit[p];
    }

    // ---- V combine ----
    const float* Vbh = Vt + ((size_t)bh << 17);
    float acc = 0.0f;
#pragma unroll
    for (int p = 0; p < 16; ++p)
        acc = fmaf(Vbh[((size_t)idx[p] << 6) + lane], logit[p], acc);
    united[((size_t)(b * C_ + c)) * HD_ + h * 64 + lane] = acc;

    // ---- attentions row: zero LDS, scatter-add, stream out ----
    const float4 z4 = make_float4(0.f, 0.f, 0.f, 0.f);
#pragma unroll
    for (int j = 0; j < 8; ++j)
        *(float4*)&rowbuf[w][(j * 64 + lane) * 4] = z4;
    __syncthreads();
    if (lane < 16) atomicAdd(&rowbuf[w][myidx], mysm);
    __syncthreads();
    float* arow = attn + ((size_t)row << 11);
#pragma unroll
    for (int j = 0; j < 8; ++j) {
        const int o = (j * 64 + lane) * 4;
        *(float4*)&arow[o] = *(const float4*)&rowbuf[w][o];
    }
}

// ---------------------------------------------------------------------------
extern "C" void kernel_launch(void* const* d_in, const int* in_sizes, int n_in,
                              void* d_out, int out_size, void* d_ws,
                              size_t ws_size, hipStream_t stream) {
    const float* x      = (const float*)d_in[0];
    // d_in[1] attention_mask: unused
    const float* means  = (const float*)d_in[2];
    const float* sigmas = (const float*)d_in[3];
    const float* values = (const float*)d_in[4];
    const float* Wk     = (const float*)d_in[5];
    const float* Wq     = (const float*)d_in[6];
    const float* Wv     = (const float*)d_in[7];
    const float* Wu     = (const float*)d_in[8];
    const float* bu     = (const float*)d_in[9];

    float* out  = (float*)d_out;                 // [0 .. 4194304) new_out
    float* attn = out + (size_t)M_ * E_;         // attentions (b,h,c,c)

    float* ws     = (float*)d_ws;
    float* Qt     = ws;                          // 2097152 floats each
    float* Kt     = ws + (size_t)2097152;
    float* Vt     = ws + (size_t)2 * 2097152;
    float* united = ws + (size_t)3 * 2097152;
    float* S      = ws + (size_t)4 * 2097152;    // 2048 floats

    hipMemsetAsync(S, 0, 2048 * sizeof(float), stream);

    gemm_qkv_kernel<<<dim3(4, 32, 3), 256, 0, stream>>>(x, Wq, Wk, Wv, Qt, Kt, Vt);
    dens_sum_kernel<<<dim3(ROWS_ / 256), 256, 0, stream>>>(means, sigmas, S);
    attn_kernel<<<dim3(ROWS_ / 4), 256, 0, stream>>>(means, sigmas, values, S,
                                                     Qt, Kt, Vt, united, attn);
    gemm_out_kernel<<<dim3(8, 32), 256, 0, stream>>>(united, Wu, bu, out);
}

// Round 2
// 423.932 us; speedup vs baseline: 1.6074x; 1.6074x over previous
//
#include <hip/hip_runtime.h>
#include <math.h>
#include <stdint.h>

#define B_ 2
#define H_ 8
#define C_ 2048
#define E_ 1024
#define D_ 64
#define KP_ 8
#define P_ 16
#define HD_ 512              // H*D
#define ROWS_ 32768          // B*H*C
#define M_ 4096              // B*C

typedef __bf16 bf16x8 __attribute__((ext_vector_type(8)));
typedef float f32x4 __attribute__((ext_vector_type(4)));
typedef uint16_t u16x8 __attribute__((ext_vector_type(8)));

__device__ inline uint16_t f2bf(float f) {
    union { float f; uint32_t u; } v; v.f = f;
    uint32_t u = v.u + 0x7FFF + ((v.u >> 16) & 1);   // RNE
    return (uint16_t)(u >> 16);
}
__device__ inline float bf2f(uint16_t h) {
    union { uint32_t u; float f; } v; v.u = ((uint32_t)h) << 16;
    return v.f;
}

// async global->LDS, 16B per lane; LDS dest = wave-uniform base + lane*16
__device__ inline void gload16(const uint16_t* g, uint16_t* l) {
    __builtin_amdgcn_global_load_lds(
        (const __attribute__((address_space(1))) void*)g,
        (__attribute__((address_space(3))) void*)l, 16, 0, 0);
}

// ---------------------------------------------------------------------------
// convert x (4096x1024 fp32) -> bf16, straight cast
// ---------------------------------------------------------------------------
__global__ __launch_bounds__(256) void convert_x_kernel(
    const float* __restrict__ in, uint16_t* __restrict__ out)
{
    const int i = (blockIdx.x * 256 + threadIdx.x) * 8;
    const float4 a = *(const float4*)(in + i);
    const float4 b = *(const float4*)(in + i + 4);
    u16x8 o;
    o[0] = f2bf(a.x); o[1] = f2bf(a.y); o[2] = f2bf(a.z); o[3] = f2bf(a.w);
    o[4] = f2bf(b.x); o[5] = f2bf(b.y); o[6] = f2bf(b.z); o[7] = f2bf(b.w);
    *(u16x8*)(out + i) = o;
}

// ---------------------------------------------------------------------------
// transpose-convert weights: in R x Cc fp32 row-major -> out Cc x R bf16
// z: 0=Wq(1024x512) 1=Wk 2=Wv 3=Wu(512x1024).  All have 512 32x32 tiles.
// ---------------------------------------------------------------------------
__global__ __launch_bounds__(256) void convert_wt_kernel(
    const float* __restrict__ Wq, const float* __restrict__ Wk,
    const float* __restrict__ Wv, const float* __restrict__ Wu,
    uint16_t* __restrict__ Wqt, uint16_t* __restrict__ Wkt,
    uint16_t* __restrict__ Wvt, uint16_t* __restrict__ Wut)
{
    const int z = blockIdx.z;
    const float* in; uint16_t* out; int R, Cc;
    if (z == 0)      { in = Wq; out = Wqt; R = E_;  Cc = HD_; }
    else if (z == 1) { in = Wk; out = Wkt; R = E_;  Cc = HD_; }
    else if (z == 2) { in = Wv; out = Wvt; R = E_;  Cc = HD_; }
    else             { in = Wu; out = Wut; R = HD_; Cc = E_; }
    const int tiles_x = Cc >> 5;
    const int tx = blockIdx.x % tiles_x;
    const int ty = blockIdx.x / tiles_x;
    const int r0 = ty * 32, c0 = tx * 32;
    __shared__ float t[32][33];
    const int lx = threadIdx.x & 31, ly = threadIdx.x >> 5;
#pragma unroll
    for (int i = 0; i < 4; ++i)
        t[ly * 4 + i][lx] = in[(size_t)(r0 + ly * 4 + i) * Cc + c0 + lx];
    __syncthreads();
#pragma unroll
    for (int i = 0; i < 4; ++i)
        out[(size_t)(c0 + ly * 4 + i) * R + r0 + lx] = f2bf(t[lx][ly * 4 + i]);
}

// ---------------------------------------------------------------------------
// GEMM 1 (MFMA bf16): x_bf16 (4096x1024) @ W^T-rows (512x1024) -> Q/K/V bf16
// in (b,h,c,d) layout, Q/K scaled by 1/8.  128x128 tile, BK=32, 4 waves.
// ---------------------------------------------------------------------------
__global__ __launch_bounds__(256) void gemm_qkv_kernel(
    const uint16_t* __restrict__ xb,
    const uint16_t* __restrict__ Wqt, const uint16_t* __restrict__ Wkt,
    const uint16_t* __restrict__ Wvt,
    uint16_t* __restrict__ Qt, uint16_t* __restrict__ Kt,
    uint16_t* __restrict__ Vt)
{
    const int z = blockIdx.z;
    const uint16_t* __restrict__ Wt = (z == 0) ? Wqt : (z == 1) ? Wkt : Wvt;
    uint16_t* __restrict__ Out = (z == 0) ? Qt : (z == 1) ? Kt : Vt;
    const float scale = (z == 2) ? 1.0f : 0.125f;
    const int K = E_;                       // 1024
    const int m0 = blockIdx.y * 128;
    const int n0 = blockIdx.x * 128;        // N=512

    __shared__ __align__(16) uint16_t As[128 * 32];
    __shared__ __align__(16) uint16_t Bs[128 * 32];

    const int tid = threadIdx.x;
    const int w = tid >> 6, lane = tid & 63;
    const int wm = w & 1, wn = w >> 1;

    f32x4 acc[4][4] = {};

    // staging: chunk ci = w*2+q covers rows [ci*16, ci*16+16), 1KB per wave-instr
    const int r0s = (w * 2 + 0) * 16 + (lane >> 2);
    const int r1s = (w * 2 + 1) * 16 + (lane >> 2);
    const int ko  = (lane & 3) * 8;
    const uint16_t* gA0 = xb + (size_t)(m0 + r0s) * K + ko;
    const uint16_t* gA1 = xb + (size_t)(m0 + r1s) * K + ko;
    const uint16_t* gB0 = Wt + (size_t)(n0 + r0s) * K + ko;
    const uint16_t* gB1 = Wt + (size_t)(n0 + r1s) * K + ko;
    uint16_t* lA0 = &As[(w * 2 + 0) * 512];
    uint16_t* lA1 = &As[(w * 2 + 1) * 512];
    uint16_t* lB0 = &Bs[(w * 2 + 0) * 512];
    uint16_t* lB1 = &Bs[(w * 2 + 1) * 512];

    const int fr = lane & 15;
    const int fk = (lane >> 4) * 8;

    for (int k0 = 0; k0 < K; k0 += 32) {
        __syncthreads();                    // prior tile reads drained
        gload16(gA0 + k0, lA0);
        gload16(gA1 + k0, lA1);
        gload16(gB0 + k0, lB0);
        gload16(gB1 + k0, lB1);
        __syncthreads();                    // vmcnt drained -> LDS valid
        bf16x8 af[4], bf[4];
#pragma unroll
        for (int t = 0; t < 4; ++t) {
            af[t] = *(const bf16x8*)&As[(wm * 64 + t * 16 + fr) * 32 + fk];
            bf[t] = *(const bf16x8*)&Bs[(wn * 64 + t * 16 + fr) * 32 + fk];
        }
#pragma unroll
        for (int mt = 0; mt < 4; ++mt)
#pragma unroll
            for (int nt = 0; nt < 4; ++nt)
                acc[mt][nt] = __builtin_amdgcn_mfma_f32_16x16x32_bf16(
                    af[mt], bf[nt], acc[mt][nt], 0, 0, 0);
    }

    // epilogue: store (b,h,c,d) bf16 with scale
#pragma unroll
    for (int mt = 0; mt < 4; ++mt) {
#pragma unroll
        for (int nt = 0; nt < 4; ++nt) {
            const int n = n0 + wn * 64 + nt * 16 + fr;
            const int h = n >> 6, d = n & 63;
#pragma unroll
            for (int r = 0; r < 4; ++r) {
                const int m = m0 + wm * 64 + mt * 16 + (lane >> 4) * 4 + r;
                const int b = m >> 11, c = m & (C_ - 1);
                Out[(((size_t)(b * H_ + h) * C_ + c) << 6) + d] =
                    f2bf(acc[mt][nt][r] * scale);
            }
        }
    }
}

// ---------------------------------------------------------------------------
// GEMM 2 (MFMA bf16): united (4096x512 bf16) @ Wu^T-rows (1024x512) + bu
// ---------------------------------------------------------------------------
__global__ __launch_bounds__(256) void gemm_out_kernel(
    const uint16_t* __restrict__ U, const uint16_t* __restrict__ Wut,
    const float* __restrict__ bu, float* __restrict__ out)
{
    const int K = HD_;                      // 512
    const int m0 = blockIdx.y * 128;
    const int n0 = blockIdx.x * 128;        // N=1024

    __shared__ __align__(16) uint16_t As[128 * 32];
    __shared__ __align__(16) uint16_t Bs[128 * 32];

    const int tid = threadIdx.x;
    const int w = tid >> 6, lane = tid & 63;
    const int wm = w & 1, wn = w >> 1;

    f32x4 acc[4][4] = {};

    const int r0s = (w * 2 + 0) * 16 + (lane >> 2);
    const int r1s = (w * 2 + 1) * 16 + (lane >> 2);
    const int ko  = (lane & 3) * 8;
    const uint16_t* gA0 = U + (size_t)(m0 + r0s) * K + ko;
    const uint16_t* gA1 = U + (size_t)(m0 + r1s) * K + ko;
    const uint16_t* gB0 = Wut + (size_t)(n0 + r0s) * K + ko;
    const uint16_t* gB1 = Wut + (size_t)(n0 + r1s) * K + ko;
    uint16_t* lA0 = &As[(w * 2 + 0) * 512];
    uint16_t* lA1 = &As[(w * 2 + 1) * 512];
    uint16_t* lB0 = &Bs[(w * 2 + 0) * 512];
    uint16_t* lB1 = &Bs[(w * 2 + 1) * 512];

    const int fr = lane & 15;
    const int fk = (lane >> 4) * 8;

    for (int k0 = 0; k0 < K; k0 += 32) {
        __syncthreads();
        gload16(gA0 + k0, lA0);
        gload16(gA1 + k0, lA1);
        gload16(gB0 + k0, lB0);
        gload16(gB1 + k0, lB1);
        __syncthreads();
        bf16x8 af[4], bf[4];
#pragma unroll
        for (int t = 0; t < 4; ++t) {
            af[t] = *(const bf16x8*)&As[(wm * 64 + t * 16 + fr) * 32 + fk];
            bf[t] = *(const bf16x8*)&Bs[(wn * 64 + t * 16 + fr) * 32 + fk];
        }
#pragma unroll
        for (int mt = 0; mt < 4; ++mt)
#pragma unroll
            for (int nt = 0; nt < 4; ++nt)
                acc[mt][nt] = __builtin_amdgcn_mfma_f32_16x16x32_bf16(
                    af[mt], bf[nt], acc[mt][nt], 0, 0, 0);
    }

#pragma unroll
    for (int mt = 0; mt < 4; ++mt) {
#pragma unroll
        for (int nt = 0; nt < 4; ++nt) {
            const int n = n0 + wn * 64 + nt * 16 + fr;
            const float bias = bu[n];
#pragma unroll
            for (int r = 0; r < 4; ++r) {
                const int m = m0 + wm * 64 + mt * 16 + (lane >> 4) * 4 + r;
                out[(size_t)m * E_ + n] = acc[mt][nt][r] + bias;
            }
        }
    }
}

// ---------------------------------------------------------------------------
// density sums over the context axis (unchanged from R1: ~5 us)
// ---------------------------------------------------------------------------
__global__ __launch_bounds__(256) void dens_sum_kernel(
    const float* __restrict__ means, const float* __restrict__ sigmas,
    float* __restrict__ S)
{
    const int row = blockIdx.x * 256 + threadIdx.x;
    const int lane = threadIdx.x & 63;
    const int bh = row >> 11;

    const float* mrow = means + (size_t)row * 8;
    const float* srow = sigmas + (size_t)row * 8;
    const float4 ma = *(const float4*)(mrow);
    const float4 mb = *(const float4*)(mrow + 4);
    const float4 sa = *(const float4*)(srow);
    const float4 sb = *(const float4*)(srow + 4);
    const float mm[8] = {ma.x, ma.y, ma.z, ma.w, mb.x, mb.y, mb.z, mb.w};
    const float sg[8] = {sa.x, sa.y, sa.z, sa.w, sb.x, sb.y, sb.z, sb.w};

    int idx[16];
#pragma unroll
    for (int j = 0; j < 8; ++j) {
        int i0 = (int)floorf(mm[j]);
        i0 = min(max(i0, 0), C_ - 1);
        idx[2 * j] = i0;
        idx[2 * j + 1] = min(i0 + 1, C_ - 1);
    }
    unsigned dupm = 0;
#pragma unroll
    for (int p = 1; p < 16; ++p) {
        bool d = false;
#pragma unroll
        for (int q = 0; q < 15; ++q)
            if (q < p) d = d || (idx[q] == idx[p]);
        if (d) dupm |= (1u << p);
    }

#pragma unroll
    for (int p = 0; p < 16; ++p) {
        const float fi = (float)idx[p];
        const bool dup = (dupm >> p) & 1u;
#pragma unroll
        for (int kk = 0; kk < 8; ++kk) {
            const float t = (fi - mm[kk]) / sg[kk];
            float val = dup ? 0.0f : expf(-0.5f * t * t);
#pragma unroll
            for (int off = 1; off < 64; off <<= 1)
                val += __shfl_xor(val, off);
            if (lane == 0)
                atomicAdd(&S[bh * 128 + p * 8 + kk], val);
        }
    }
}

// ---------------------------------------------------------------------------
// attention core, restructured dots: lane=(p,g), p=lane>>2 point, g=lane&3
// covers dims [g*16, g*16+16).  2-step g-reduce + 8-step p-softmax-reduce.
// ---------------------------------------------------------------------------
__global__ __launch_bounds__(256) void attn_kernel(
    const float* __restrict__ means, const float* __restrict__ sigmas,
    const float* __restrict__ values, const float* __restrict__ S,
    const uint16_t* __restrict__ Qt, const uint16_t* __restrict__ Kt,
    const uint16_t* __restrict__ Vt, uint16_t* __restrict__ united,
    float* __restrict__ attn)
{
    __shared__ float rowbuf[4][2048];
    const int w = threadIdx.x >> 6;
    const int lane = threadIdx.x & 63;
    const int row = blockIdx.x * 4 + w;
    const int bh = row >> 11;
    const int c = row & (C_ - 1);
    const int b = bh >> 3;
    const int h = bh & 7;

    const float* mrow = means + (size_t)row * 8;
    const float4 ma = *(const float4*)(mrow);
    const float4 mb = *(const float4*)(mrow + 4);
    const float mm[8] = {ma.x, ma.y, ma.z, ma.w, mb.x, mb.y, mb.z, mb.w};

    int idx[16];
#pragma unroll
    for (int j = 0; j < 8; ++j) {
        int i0 = (int)floorf(mm[j]);
        i0 = min(max(i0, 0), C_ - 1);
        idx[2 * j] = i0;
        idx[2 * j + 1] = min(i0 + 1, C_ - 1);
    }

    // ---- per-point weights on lanes 0..15 ----
    const int lp = lane & 15;
    int myidx = 0;
#pragma unroll
    for (int q = 0; q < 16; ++q)
        if (q == lp) myidx = idx[q];
    float wp = 0.0f;
    if (lane < 16) {
        bool dup = false;
#pragma unroll
        for (int q = 0; q < 15; ++q)
            dup = dup || ((q < lane) && (idx[q] == myidx));
        if (!dup) {
            const float* srow = sigmas + (size_t)row * 8;
            const float* vrow = values + (size_t)row * 8;
            const float4 sa = *(const float4*)(srow);
            const float4 sb = *(const float4*)(srow + 4);
            const float4 va = *(const float4*)(vrow);
            const float4 vb = *(const float4*)(vrow + 4);
            const float sg[8] = {sa.x, sa.y, sa.z, sa.w, sb.x, sb.y, sb.z, sb.w};
            const float vl[8] = {va.x, va.y, va.z, va.w, vb.x, vb.y, vb.z, vb.w};
            const float* Sp = S + bh * 128 + lane * 8;
            const float4 Sa = *(const float4*)(Sp);
            const float4 Sb = *(const float4*)(Sp + 4);
            const float Sv[8] = {Sa.x, Sa.y, Sa.z, Sa.w, Sb.x, Sb.y, Sb.z, Sb.w};
            const float fi = (float)myidx;
#pragma unroll
            for (int kk = 0; kk < 8; ++kk) {
                const float t = (fi - mm[kk]) / sg[kk];
                const float e = expf(-0.5f * t * t);
                wp = fmaf(vl[kk], e / (Sv[kk] + 1e-8f), wp);
            }
        }
    }

    // ---- dots in (p,g) layout ----
    const int p = lane >> 2, g = lane & 3;
    int kidx = 0;
#pragma unroll
    for (int q = 0; q < 16; ++q)
        if (q == p) kidx = idx[q];

    const uint16_t* Qrow = Qt + ((size_t)row << 6);
    const uint16_t* Krow = Kt + ((((size_t)bh << 11) + kidx) << 6);
    const u16x8 qa = *(const u16x8*)(Qrow + g * 16);
    const u16x8 qb = *(const u16x8*)(Qrow + g * 16 + 8);
    const u16x8 ka = *(const u16x8*)(Krow + g * 16);
    const u16x8 kb = *(const u16x8*)(Krow + g * 16 + 8);
    float dot = 0.0f;
#pragma unroll
    for (int j = 0; j < 8; ++j) {
        dot = fmaf(bf2f(qa[j]), bf2f(ka[j]), dot);
        dot = fmaf(bf2f(qb[j]), bf2f(kb[j]), dot);
    }
    dot += __shfl_xor(dot, 1);
    dot += __shfl_xor(dot, 2);              // all 4 lanes of group p: full dot

    const float wvp = __shfl(wp, p);
    const float logit = wvp * dot;

    // softmax across p (xor over bits 2..5 touches each p exactly once)
    float mx = logit;
#pragma unroll
    for (int off = 4; off < 64; off <<= 1)
        mx = fmaxf(mx, __shfl_xor(mx, off));
    const float e = expf(logit - mx);
    float se = e;
#pragma unroll
    for (int off = 4; off < 64; off <<= 1)
        se += __shfl_xor(se, off);
    const float sm = e / se;                // softmax weight of point p

    // broadcast all 16 sm to every lane
    float smv[16];
#pragma unroll
    for (int q = 0; q < 16; ++q)
        smv[q] = __shfl(sm, q * 4);

    // ---- V combine (lane = d) ----
    const uint16_t* Vbh = Vt + ((size_t)bh << 17);
    float acc = 0.0f;
#pragma unroll
    for (int q = 0; q < 16; ++q)
        acc = fmaf(bf2f(Vbh[((size_t)idx[q] << 6) + lane]), smv[q], acc);
    united[((size_t)(b * C_ + c)) * HD_ + h * 64 + lane] = f2bf(acc);

    // ---- attentions row via LDS scatter ----
    const float4 z4 = make_float4(0.f, 0.f, 0.f, 0.f);
#pragma unroll
    for (int j = 0; j < 8; ++j)
        *(float4*)&rowbuf[w][(j * 64 + lane) * 4] = z4;
    __syncthreads();
    if (lane < 16) atomicAdd(&rowbuf[w][myidx], smv[lane]);
    __syncthreads();
    float* arow = attn + ((size_t)row << 11);
#pragma unroll
    for (int j = 0; j < 8; ++j) {
        const int o = (j * 64 + lane) * 4;
        *(float4*)&arow[o] = *(const float4*)&rowbuf[w][o];
    }
}

// ---------------------------------------------------------------------------
extern "C" void kernel_launch(void* const* d_in, const int* in_sizes, int n_in,
                              void* d_out, int out_size, void* d_ws,
                              size_t ws_size, hipStream_t stream) {
    const float* x      = (const float*)d_in[0];
    const float* means  = (const float*)d_in[2];
    const float* sigmas = (const float*)d_in[3];
    const float* values = (const float*)d_in[4];
    const float* Wk     = (const float*)d_in[5];
    const float* Wq     = (const float*)d_in[6];
    const float* Wv     = (const float*)d_in[7];
    const float* Wu     = (const float*)d_in[8];
    const float* bu     = (const float*)d_in[9];

    float* out  = (float*)d_out;
    float* attn = out + (size_t)M_ * E_;

    // workspace (uint16 elements): total 28 MB
    uint16_t* wsp = (uint16_t*)d_ws;
    uint16_t* xb     = wsp;                              // 4194304
    uint16_t* Wqt    = xb + 4194304;                     // 524288
    uint16_t* Wkt    = Wqt + 524288;
    uint16_t* Wvt    = Wkt + 524288;
    uint16_t* Wut    = Wvt + 524288;                     // 524288
    uint16_t* Qt     = Wut + 524288;                     // 2097152
    uint16_t* Kt     = Qt + 2097152;
    uint16_t* Vt     = Kt + 2097152;
    uint16_t* united = Vt + 2097152;                     // 2097152
    float*    S      = (float*)(united + 2097152);       // 2048 floats

    hipMemsetAsync(S, 0, 2048 * sizeof(float), stream);

    convert_x_kernel<<<2048, 256, 0, stream>>>(x, xb);
    convert_wt_kernel<<<dim3(512, 1, 4), 256, 0, stream>>>(
        Wq, Wk, Wv, Wu, Wqt, Wkt, Wvt, Wut);
    dens_sum_kernel<<<128, 256, 0, stream>>>(means, sigmas, S);
    gemm_qkv_kernel<<<dim3(4, 32, 3), 256, 0, stream>>>(
        xb, Wqt, Wkt, Wvt, Qt, Kt, Vt);
    attn_kernel<<<ROWS_ / 4, 256, 0, stream>>>(
        means, sigmas, values, S, Qt, Kt, Vt, united, attn);
    gemm_out_kernel<<<dim3(8, 32), 256, 0, stream>>>(united, Wut, bu, out);
}